// Round 1
// baseline (544.226 us; speedup 1.0000x reference)
//
#include <hip/hip_runtime.h>

#define N_PTS 2097152
#define GRID_ 512
#define F_FEAT 32
#define HW (GRID_ * GRID_)
#define HWF ((size_t)HW * F_FEAT) // floats per transposed plane = 8388608

// ---------------------------------------------------------------------------
// Kernel 0: scale[f] = sum_k core[k][f]   (core is (16, 32))
// ---------------------------------------------------------------------------
__global__ void td_scale_kernel(const float* __restrict__ core,
                                float* __restrict__ scale) {
    int f = threadIdx.x; // 32 threads
    float s = 0.0f;
#pragma unroll
    for (int k = 0; k < 16; ++k) s += core[k * F_FEAT + f];
    scale[f] = s;
}

// ---------------------------------------------------------------------------
// Kernel 1: transpose (F, H, W) -> (H, W, F). Plane 0 folds scale[f] in.
// Block (32,8): one block handles (y fixed, 32 x-positions, all 32 f).
// ---------------------------------------------------------------------------
__global__ void td_transpose_kernel(const float* __restrict__ pxy,
                                    const float* __restrict__ pyz,
                                    const float* __restrict__ pxz,
                                    const float* __restrict__ scale,
                                    float* __restrict__ ws) {
    __shared__ float tile[32][33]; // +1 pad: conflict-free
    const int plane = blockIdx.z;
    const float* src = (plane == 0) ? pxy : ((plane == 1) ? pyz : pxz);
    float* dst = ws + (size_t)plane * HWF;
    const int y = blockIdx.y;
    const int x0 = blockIdx.x * 32;

    // read phase: coalesced in x; i walks features
    for (int i = threadIdx.y; i < 32; i += 8) {
        tile[i][threadIdx.x] =
            src[(size_t)i * HW + (size_t)y * GRID_ + x0 + threadIdx.x];
    }
    __syncthreads();
    const float sc = (plane == 0) ? scale[threadIdx.x] : 1.0f;
    // write phase: threadIdx.x walks features -> coalesced (H,W,F) writes
    for (int i = threadIdx.y; i < 32; i += 8) {
        dst[((size_t)(y * GRID_ + x0 + i)) * F_FEAT + threadIdx.x] =
            tile[threadIdx.x][i] * sc;
    }
}

// ---------------------------------------------------------------------------
// Kernel 2: sampling. 8 lanes per point, each lane owns 4 features (float4).
// Corner reads: 8 lanes x 16B = one 128B coalesced line per corner.
// ---------------------------------------------------------------------------
__global__ __launch_bounds__(256) void td_sample_kernel(
    const float2* __restrict__ coords, // (3*N) float2
    const float4* __restrict__ ws,     // 3 planes, (H*W*8) float4 each
    float4* __restrict__ out)          // N*8 float4
{
    const int tid = blockIdx.x * 256 + threadIdx.x;
    const int p = tid >> 3;
    const int fq = tid & 7;

    float px = 1.0f, py = 1.0f, pz = 1.0f, pw = 1.0f;

#pragma unroll
    for (int plane = 0; plane < 3; ++plane) {
        const float2 c = coords[(size_t)plane * N_PTS + p];
        const float xf = (c.x + 1.0f) * 0.5f * (float)(GRID_ - 1);
        const float yf = (c.y + 1.0f) * 0.5f * (float)(GRID_ - 1);
        const float x0f = floorf(xf);
        const float y0f = floorf(yf);
        const float wx = xf - x0f;
        const float wy = yf - y0f;
        int x0 = (int)x0f;
        int y0 = (int)y0f;
        x0 = min(max(x0, 0), GRID_ - 1);
        y0 = min(max(y0, 0), GRID_ - 1);
        const int x1 = min(x0 + 1, GRID_ - 1);
        const int y1 = min(y0 + 1, GRID_ - 1);

        const float4* tp = ws + (size_t)plane * (HWF / 4);
        const float4 v00 = tp[(size_t)(y0 * GRID_ + x0) * 8 + fq];
        const float4 v01 = tp[(size_t)(y0 * GRID_ + x1) * 8 + fq];
        const float4 v10 = tp[(size_t)(y1 * GRID_ + x0) * 8 + fq];
        const float4 v11 = tp[(size_t)(y1 * GRID_ + x1) * 8 + fq];

        const float w00 = (1.0f - wx) * (1.0f - wy);
        const float w01 = wx * (1.0f - wy);
        const float w10 = (1.0f - wx) * wy;
        const float w11 = wx * wy;

        const float sx = v00.x * w00 + v01.x * w01 + v10.x * w10 + v11.x * w11;
        const float sy = v00.y * w00 + v01.y * w01 + v10.y * w10 + v11.y * w11;
        const float sz = v00.z * w00 + v01.z * w01 + v10.z * w10 + v11.z * w11;
        const float sw = v00.w * w00 + v01.w * w01 + v10.w * w10 + v11.w * w11;

        px *= sx;
        py *= sy;
        pz *= sz;
        pw *= sw;
    }

    float4 r;
    r.x = px; r.y = py; r.z = pz; r.w = pw;
    out[tid] = r; // tid == p*8 + fq
}

// ---------------------------------------------------------------------------
// Fallback (workspace too small): direct strided gather from (F,H,W).
// ---------------------------------------------------------------------------
__global__ __launch_bounds__(256) void td_fallback_kernel(
    const float* __restrict__ coords, const float* __restrict__ pxy,
    const float* __restrict__ pyz, const float* __restrict__ pxz,
    const float* __restrict__ core, float* __restrict__ out) {
    const int tid = blockIdx.x * 256 + threadIdx.x;
    const int p = tid >> 5;
    const int f = tid & 31;

    float s = 0.0f;
#pragma unroll
    for (int k = 0; k < 16; ++k) s += core[k * F_FEAT + f];

    float prod = s;
    const float* planes[3] = {pxy, pyz, pxz};
#pragma unroll
    for (int plane = 0; plane < 3; ++plane) {
        const float cx = coords[((size_t)plane * N_PTS + p) * 2 + 0];
        const float cy = coords[((size_t)plane * N_PTS + p) * 2 + 1];
        const float xf = (cx + 1.0f) * 0.5f * (float)(GRID_ - 1);
        const float yf = (cy + 1.0f) * 0.5f * (float)(GRID_ - 1);
        const float x0f = floorf(xf);
        const float y0f = floorf(yf);
        const float wx = xf - x0f;
        const float wy = yf - y0f;
        int x0 = (int)x0f;
        int y0 = (int)y0f;
        x0 = min(max(x0, 0), GRID_ - 1);
        y0 = min(max(y0, 0), GRID_ - 1);
        const int x1 = min(x0 + 1, GRID_ - 1);
        const int y1 = min(y0 + 1, GRID_ - 1);
        const float* src = planes[plane] + (size_t)f * HW;
        const float v00 = src[y0 * GRID_ + x0];
        const float v01 = src[y0 * GRID_ + x1];
        const float v10 = src[y1 * GRID_ + x0];
        const float v11 = src[y1 * GRID_ + x1];
        const float v = v00 * (1.0f - wx) * (1.0f - wy) + v01 * wx * (1.0f - wy) +
                        v10 * (1.0f - wx) * wy + v11 * wx * wy;
        prod *= v;
    }
    out[(size_t)p * F_FEAT + f] = prod;
}

extern "C" void kernel_launch(void* const* d_in, const int* in_sizes, int n_in,
                              void* d_out, int out_size, void* d_ws,
                              size_t ws_size, hipStream_t stream) {
    const float* coords = (const float*)d_in[0];
    const float* pxy = (const float*)d_in[1];
    const float* pyz = (const float*)d_in[2];
    const float* pxz = (const float*)d_in[3];
    const float* core = (const float*)d_in[4];
    float* out = (float*)d_out;

    const size_t need = (3 * HWF + 32) * sizeof(float);
    if (ws_size >= need) {
        float* ws = (float*)d_ws;
        float* scale = ws + 3 * HWF;
        td_scale_kernel<<<1, 32, 0, stream>>>(core, scale);
        td_transpose_kernel<<<dim3(GRID_ / 32, GRID_, 3), dim3(32, 8), 0,
                              stream>>>(pxy, pyz, pxz, scale, ws);
        const int total = N_PTS * 8; // threads (point x feature-quad)
        td_sample_kernel<<<total / 256, 256, 0, stream>>>(
            (const float2*)coords, (const float4*)ws, (float4*)out);
    } else {
        const int total = N_PTS * 32;
        td_fallback_kernel<<<total / 256, 256, 0, stream>>>(coords, pxy, pyz,
                                                            pxz, core, out);
    }
}

// Round 2
// 440.445 us; speedup vs baseline: 1.2356x; 1.2356x over previous
//
#include <hip/hip_runtime.h>
#include <hip/hip_fp16.h>

#define N_PTS 2097152
#define GRID_ 512
#define F_FEAT 32
#define HW (GRID_ * GRID_)
#define HWF ((size_t)HW * F_FEAT) // elements per transposed plane = 8388608

// ---------------------------------------------------------------------------
// Kernel 0: scale[f] = sum_k core[k][f]   (core is (16, 32))
// ---------------------------------------------------------------------------
__global__ void td_scale_kernel(const float* __restrict__ core,
                                float* __restrict__ scale) {
    int f = threadIdx.x; // 32 threads
    float s = 0.0f;
#pragma unroll
    for (int k = 0; k < 16; ++k) s += core[k * F_FEAT + f];
    scale[f] = s;
}

// ---------------------------------------------------------------------------
// Kernel 1: transpose (F, H, W) f32 -> (H, W, F) fp16. Plane 0 folds scale in.
// Block (32,8): one block handles (y fixed, 32 x-positions, all 32 f).
// ---------------------------------------------------------------------------
__global__ void td_transpose_kernel(const float* __restrict__ pxy,
                                    const float* __restrict__ pyz,
                                    const float* __restrict__ pxz,
                                    const float* __restrict__ scale,
                                    __half* __restrict__ wsh) {
    __shared__ float tile[32][33]; // +1 pad: conflict-free
    const int plane = blockIdx.z;
    const float* src = (plane == 0) ? pxy : ((plane == 1) ? pyz : pxz);
    __half* dst = wsh + (size_t)plane * HWF;
    const int y = blockIdx.y;
    const int x0 = blockIdx.x * 32;

    // read phase: coalesced in x; i walks features
    for (int i = threadIdx.y; i < 32; i += 8) {
        tile[i][threadIdx.x] =
            src[(size_t)i * HW + (size_t)y * GRID_ + x0 + threadIdx.x];
    }
    __syncthreads();
    const float sc = (plane == 0) ? scale[threadIdx.x] : 1.0f;
    // write phase: threadIdx.x walks features -> contiguous (H,W,F) writes
    for (int i = threadIdx.y; i < 32; i += 8) {
        dst[((size_t)(y * GRID_ + x0 + i)) * F_FEAT + threadIdx.x] =
            __float2half(tile[threadIdx.x][i] * sc);
    }
}

// ---------------------------------------------------------------------------
// Kernel 2: sampling. 4 lanes per point; each lane owns 8 features, loaded as
// one float4 (= 8 halves = 16B) per corner. 4 lanes x 16B = one 64B texel.
// ---------------------------------------------------------------------------
__global__ __launch_bounds__(256) void td_sample_kernel(
    const float2* __restrict__ coords, // (3*N) float2
    const float4* __restrict__ ws4,    // 3 fp16 planes, texel = 4 float4
    float4* __restrict__ out)          // N*8 float4 (f32)
{
    const int tid = blockIdx.x * 256 + threadIdx.x;
    const int p = tid >> 2;
    const int fq = tid & 3; // feature octet: features fq*8 .. fq*8+7

    float prod[8];
#pragma unroll
    for (int j = 0; j < 8; ++j) prod[j] = 1.0f;

#pragma unroll
    for (int plane = 0; plane < 3; ++plane) {
        const float2 c = coords[(size_t)plane * N_PTS + p];
        const float xf = (c.x + 1.0f) * 0.5f * (float)(GRID_ - 1);
        const float yf = (c.y + 1.0f) * 0.5f * (float)(GRID_ - 1);
        const float x0f = floorf(xf);
        const float y0f = floorf(yf);
        const float wx = xf - x0f;
        const float wy = yf - y0f;
        int x0 = (int)x0f;
        int y0 = (int)y0f;
        x0 = min(max(x0, 0), GRID_ - 1);
        y0 = min(max(y0, 0), GRID_ - 1);
        const int x1 = min(x0 + 1, GRID_ - 1);
        const int y1 = min(y0 + 1, GRID_ - 1);

        // texel t at (y,x): float4 index (y*512+x)*4 + fq
        const float4* tp = ws4 + (size_t)plane * (HWF / 8);
        const float4 r00 = tp[(size_t)(y0 * GRID_ + x0) * 4 + fq];
        const float4 r01 = tp[(size_t)(y0 * GRID_ + x1) * 4 + fq];
        const float4 r10 = tp[(size_t)(y1 * GRID_ + x0) * 4 + fq];
        const float4 r11 = tp[(size_t)(y1 * GRID_ + x1) * 4 + fq];

        const float w00 = (1.0f - wx) * (1.0f - wy);
        const float w01 = wx * (1.0f - wy);
        const float w10 = (1.0f - wx) * wy;
        const float w11 = wx * wy;

        const half2* h00 = reinterpret_cast<const half2*>(&r00);
        const half2* h01 = reinterpret_cast<const half2*>(&r01);
        const half2* h10 = reinterpret_cast<const half2*>(&r10);
        const half2* h11 = reinterpret_cast<const half2*>(&r11);

#pragma unroll
        for (int j = 0; j < 4; ++j) {
            const float2 f00 = __half22float2(h00[j]);
            const float2 f01 = __half22float2(h01[j]);
            const float2 f10 = __half22float2(h10[j]);
            const float2 f11 = __half22float2(h11[j]);
            const float sa =
                f00.x * w00 + f01.x * w01 + f10.x * w10 + f11.x * w11;
            const float sb =
                f00.y * w00 + f01.y * w01 + f10.y * w10 + f11.y * w11;
            prod[2 * j] *= sa;
            prod[2 * j + 1] *= sb;
        }
    }

    float4 o0, o1;
    o0.x = prod[0]; o0.y = prod[1]; o0.z = prod[2]; o0.w = prod[3];
    o1.x = prod[4]; o1.y = prod[5]; o1.z = prod[6]; o1.w = prod[7];
    out[(size_t)tid * 2] = o0;
    out[(size_t)tid * 2 + 1] = o1;
}

// ---------------------------------------------------------------------------
// Fallback (workspace too small): direct strided gather from (F,H,W), f32.
// ---------------------------------------------------------------------------
__global__ __launch_bounds__(256) void td_fallback_kernel(
    const float* __restrict__ coords, const float* __restrict__ pxy,
    const float* __restrict__ pyz, const float* __restrict__ pxz,
    const float* __restrict__ core, float* __restrict__ out) {
    const int tid = blockIdx.x * 256 + threadIdx.x;
    const int p = tid >> 5;
    const int f = tid & 31;

    float s = 0.0f;
#pragma unroll
    for (int k = 0; k < 16; ++k) s += core[k * F_FEAT + f];

    float prod = s;
    const float* planes[3] = {pxy, pyz, pxz};
#pragma unroll
    for (int plane = 0; plane < 3; ++plane) {
        const float cx = coords[((size_t)plane * N_PTS + p) * 2 + 0];
        const float cy = coords[((size_t)plane * N_PTS + p) * 2 + 1];
        const float xf = (cx + 1.0f) * 0.5f * (float)(GRID_ - 1);
        const float yf = (cy + 1.0f) * 0.5f * (float)(GRID_ - 1);
        const float x0f = floorf(xf);
        const float y0f = floorf(yf);
        const float wx = xf - x0f;
        const float wy = yf - y0f;
        int x0 = (int)x0f;
        int y0 = (int)y0f;
        x0 = min(max(x0, 0), GRID_ - 1);
        y0 = min(max(y0, 0), GRID_ - 1);
        const int x1 = min(x0 + 1, GRID_ - 1);
        const int y1 = min(y0 + 1, GRID_ - 1);
        const float* src = planes[plane] + (size_t)f * HW;
        const float v00 = src[y0 * GRID_ + x0];
        const float v01 = src[y0 * GRID_ + x1];
        const float v10 = src[y1 * GRID_ + x0];
        const float v11 = src[y1 * GRID_ + x1];
        const float v = v00 * (1.0f - wx) * (1.0f - wy) + v01 * wx * (1.0f - wy) +
                        v10 * (1.0f - wx) * wy + v11 * wx * wy;
        prod *= v;
    }
    out[(size_t)p * F_FEAT + f] = prod;
}

extern "C" void kernel_launch(void* const* d_in, const int* in_sizes, int n_in,
                              void* d_out, int out_size, void* d_ws,
                              size_t ws_size, hipStream_t stream) {
    const float* coords = (const float*)d_in[0];
    const float* pxy = (const float*)d_in[1];
    const float* pyz = (const float*)d_in[2];
    const float* pxz = (const float*)d_in[3];
    const float* core = (const float*)d_in[4];
    float* out = (float*)d_out;

    // fp16 planes: 3 * HWF halves, then 32 floats of scale
    const size_t need = 3 * HWF * sizeof(__half) + 32 * sizeof(float);
    if (ws_size >= need) {
        __half* wsh = (__half*)d_ws;
        float* scale = (float*)(wsh + 3 * HWF);
        td_scale_kernel<<<1, 32, 0, stream>>>(core, scale);
        td_transpose_kernel<<<dim3(GRID_ / 32, GRID_, 3), dim3(32, 8), 0,
                              stream>>>(pxy, pyz, pxz, scale, wsh);
        const int total = N_PTS * 4; // threads (point x feature-octet)
        td_sample_kernel<<<total / 256, 256, 0, stream>>>(
            (const float2*)coords, (const float4*)wsh, (float4*)out);
    } else {
        const int total = N_PTS * 32;
        td_fallback_kernel<<<total / 256, 256, 0, stream>>>(coords, pxy, pyz,
                                                            pxz, core, out);
    }
}

// Round 4
// 401.028 us; speedup vs baseline: 1.3571x; 1.0983x over previous
//
#include <hip/hip_runtime.h>
#include <hip/hip_fp16.h>

#define N_PTS 2097152
#define GRID_ 512
#define F_FEAT 32
#define HW (GRID_ * GRID_)
#define HWF ((size_t)HW * F_FEAT) // elements per transposed plane = 8388608

typedef float f32x4 __attribute__((ext_vector_type(4)));

// ---------------------------------------------------------------------------
// Kernel 0: scale[f] = sum_k core[k][f]   (core is (16, 32))
// ---------------------------------------------------------------------------
__global__ void td_scale_kernel(const float* __restrict__ core,
                                float* __restrict__ scale) {
    int f = threadIdx.x; // 32 threads
    float s = 0.0f;
#pragma unroll
    for (int k = 0; k < 16; ++k) s += core[k * F_FEAT + f];
    scale[f] = s;
}

// ---------------------------------------------------------------------------
// Kernel 1: transpose (F, H, W) f32 -> (H, W, F) fp16. Plane 0 folds scale in.
// ---------------------------------------------------------------------------
__global__ void td_transpose_kernel(const float* __restrict__ pxy,
                                    const float* __restrict__ pyz,
                                    const float* __restrict__ pxz,
                                    const float* __restrict__ scale,
                                    __half* __restrict__ wsh) {
    __shared__ float tile[32][33]; // +1 pad: conflict-free
    const int plane = blockIdx.z;
    const float* src = (plane == 0) ? pxy : ((plane == 1) ? pyz : pxz);
    __half* dst = wsh + (size_t)plane * HWF;
    const int y = blockIdx.y;
    const int x0 = blockIdx.x * 32;

    for (int i = threadIdx.y; i < 32; i += 8) {
        tile[i][threadIdx.x] =
            src[(size_t)i * HW + (size_t)y * GRID_ + x0 + threadIdx.x];
    }
    __syncthreads();
    const float sc = (plane == 0) ? scale[threadIdx.x] : 1.0f;
    for (int i = threadIdx.y; i < 32; i += 8) {
        dst[((size_t)(y * GRID_ + x0 + i)) * F_FEAT + threadIdx.x] =
            __float2half(tile[threadIdx.x][i] * sc);
    }
}

// ---------------------------------------------------------------------------
// Kernel 2: sampling, full-ILP. 4 lanes per point; each lane owns 8 features
// (one 16B load per corner). All 12 corner loads issued before any use.
// Output stored non-temporally (don't evict texels from L2).
// ---------------------------------------------------------------------------
__global__ __launch_bounds__(256) void td_sample_kernel(
    const float2* __restrict__ coords, // (3*N) float2
    const f32x4* __restrict__ ws4,     // 3 fp16 planes, texel = 4 x 16B
    f32x4* __restrict__ out)           // N*8 float4 (f32)
{
    const int tid = blockIdx.x * 256 + threadIdx.x;
    const int p = tid >> 2;
    const int fq = tid & 3; // feature octet

    // --- all coords up front ---
    const float2 c0 = coords[p];
    const float2 c1 = coords[N_PTS + p];
    const float2 c2 = coords[2 * N_PTS + p];

    // --- per-plane address + weight computation (no loads yet) ---
    size_t idx[3][4];
    float w[3][4];
    const float2 cc[3] = {c0, c1, c2};
#pragma unroll
    for (int pl = 0; pl < 3; ++pl) {
        const float xf = (cc[pl].x + 1.0f) * 0.5f * (float)(GRID_ - 1);
        const float yf = (cc[pl].y + 1.0f) * 0.5f * (float)(GRID_ - 1);
        const float x0f = floorf(xf);
        const float y0f = floorf(yf);
        const float wx = xf - x0f;
        const float wy = yf - y0f;
        int x0 = (int)x0f;
        int y0 = (int)y0f;
        x0 = min(max(x0, 0), GRID_ - 1);
        y0 = min(max(y0, 0), GRID_ - 1);
        const int x1 = min(x0 + 1, GRID_ - 1);
        const int y1 = min(y0 + 1, GRID_ - 1);
        const size_t base = (size_t)pl * (HWF / 8);
        idx[pl][0] = base + (size_t)(y0 * GRID_ + x0) * 4 + fq;
        idx[pl][1] = base + (size_t)(y0 * GRID_ + x1) * 4 + fq;
        idx[pl][2] = base + (size_t)(y1 * GRID_ + x0) * 4 + fq;
        idx[pl][3] = base + (size_t)(y1 * GRID_ + x1) * 4 + fq;
        w[pl][0] = (1.0f - wx) * (1.0f - wy);
        w[pl][1] = wx * (1.0f - wy);
        w[pl][2] = (1.0f - wx) * wy;
        w[pl][3] = wx * wy;
    }

    // --- issue ALL 12 corner loads ---
    f32x4 v[3][4];
#pragma unroll
    for (int pl = 0; pl < 3; ++pl)
#pragma unroll
        for (int cnr = 0; cnr < 4; ++cnr) v[pl][cnr] = ws4[idx[pl][cnr]];

    // --- combine ---
    float prod[8];
#pragma unroll
    for (int j = 0; j < 8; ++j) prod[j] = 1.0f;

#pragma unroll
    for (int pl = 0; pl < 3; ++pl) {
        const half2* h0 = reinterpret_cast<const half2*>(&v[pl][0]);
        const half2* h1 = reinterpret_cast<const half2*>(&v[pl][1]);
        const half2* h2 = reinterpret_cast<const half2*>(&v[pl][2]);
        const half2* h3 = reinterpret_cast<const half2*>(&v[pl][3]);
#pragma unroll
        for (int j = 0; j < 4; ++j) {
            const float2 f00 = __half22float2(h0[j]);
            const float2 f01 = __half22float2(h1[j]);
            const float2 f10 = __half22float2(h2[j]);
            const float2 f11 = __half22float2(h3[j]);
            const float sa = f00.x * w[pl][0] + f01.x * w[pl][1] +
                             f10.x * w[pl][2] + f11.x * w[pl][3];
            const float sb = f00.y * w[pl][0] + f01.y * w[pl][1] +
                             f10.y * w[pl][2] + f11.y * w[pl][3];
            prod[2 * j] *= sa;
            prod[2 * j + 1] *= sb;
        }
    }

    f32x4 o0, o1;
    o0.x = prod[0]; o0.y = prod[1]; o0.z = prod[2]; o0.w = prod[3];
    o1.x = prod[4]; o1.y = prod[5]; o1.z = prod[6]; o1.w = prod[7];
    __builtin_nontemporal_store(o0, &out[(size_t)tid * 2]);
    __builtin_nontemporal_store(o1, &out[(size_t)tid * 2 + 1]);
}

// ---------------------------------------------------------------------------
// Fallback (workspace too small): direct strided gather from (F,H,W), f32.
// ---------------------------------------------------------------------------
__global__ __launch_bounds__(256) void td_fallback_kernel(
    const float* __restrict__ coords, const float* __restrict__ pxy,
    const float* __restrict__ pyz, const float* __restrict__ pxz,
    const float* __restrict__ core, float* __restrict__ out) {
    const int tid = blockIdx.x * 256 + threadIdx.x;
    const int p = tid >> 5;
    const int f = tid & 31;

    float s = 0.0f;
#pragma unroll
    for (int k = 0; k < 16; ++k) s += core[k * F_FEAT + f];

    float prod = s;
    const float* planes[3] = {pxy, pyz, pxz};
#pragma unroll
    for (int plane = 0; plane < 3; ++plane) {
        const float cx = coords[((size_t)plane * N_PTS + p) * 2 + 0];
        const float cy = coords[((size_t)plane * N_PTS + p) * 2 + 1];
        const float xf = (cx + 1.0f) * 0.5f * (float)(GRID_ - 1);
        const float yf = (cy + 1.0f) * 0.5f * (float)(GRID_ - 1);
        const float x0f = floorf(xf);
        const float y0f = floorf(yf);
        const float wx = xf - x0f;
        const float wy = yf - y0f;
        int x0 = (int)x0f;
        int y0 = (int)y0f;
        x0 = min(max(x0, 0), GRID_ - 1);
        y0 = min(max(y0, 0), GRID_ - 1);
        const int x1 = min(x0 + 1, GRID_ - 1);
        const int y1 = min(y0 + 1, GRID_ - 1);
        const float* src = planes[plane] + (size_t)f * HW;
        const float v00 = src[y0 * GRID_ + x0];
        const float v01 = src[y0 * GRID_ + x1];
        const float v10 = src[y1 * GRID_ + x0];
        const float v11 = src[y1 * GRID_ + x1];
        const float v = v00 * (1.0f - wx) * (1.0f - wy) + v01 * wx * (1.0f - wy) +
                        v10 * (1.0f - wx) * wy + v11 * wx * wy;
        prod *= v;
    }
    out[(size_t)p * F_FEAT + f] = prod;
}

extern "C" void kernel_launch(void* const* d_in, const int* in_sizes, int n_in,
                              void* d_out, int out_size, void* d_ws,
                              size_t ws_size, hipStream_t stream) {
    const float* coords = (const float*)d_in[0];
    const float* pxy = (const float*)d_in[1];
    const float* pyz = (const float*)d_in[2];
    const float* pxz = (const float*)d_in[3];
    const float* core = (const float*)d_in[4];
    float* out = (float*)d_out;

    const size_t need = 3 * HWF * sizeof(__half) + 32 * sizeof(float);
    if (ws_size >= need) {
        __half* wsh = (__half*)d_ws;
        float* scale = (float*)(wsh + 3 * HWF);
        td_scale_kernel<<<1, 32, 0, stream>>>(core, scale);
        td_transpose_kernel<<<dim3(GRID_ / 32, GRID_, 3), dim3(32, 8), 0,
                              stream>>>(pxy, pyz, pxz, scale, wsh);
        const int total = N_PTS * 4; // threads (point x feature-octet)
        td_sample_kernel<<<total / 256, 256, 0, stream>>>(
            (const float2*)coords, (const f32x4*)wsh, (f32x4*)out);
    } else {
        const int total = N_PTS * 32;
        td_fallback_kernel<<<total / 256, 256, 0, stream>>>(coords, pxy, pyz,
                                                            pxz, core, out);
    }
}